// Round 6
// baseline (54.652 us; speedup 1.0000x reference)
//
#include <hip/hip_runtime.h>

#define Nn 8
#define Cc 4
#define Hh 256
#define Ww 256
#define BIGD 0x20000000

// Workspace layout (bytes):
//   g       : [n][k][j] ushort4 (per-class row distance, <=512) -> 4,194,304
//   partials: [2048] float                                      ->     8,192
//   counter : 1 uint (ticket for last-block reduction)
#define OFF_G    0
#define OFF_PART 4194304
#define OFF_CNT  4202496

// ---------------------------------------------------------------------------
// Kernel A: exact per-row 1-D nearest-class distance via 256-bit class masks.
// (unchanged; ~2us measured by subtraction in R5)
// ---------------------------------------------------------------------------
__global__ __launch_bounds__(1024) void edt_rows_kernel(
    const int* __restrict__ tgt, ushort4* __restrict__ g,
    unsigned* __restrict__ counter) {
  // [row][class][guard0, w0..w3, guard5, pad] ; stride 7 -> <=2-way (free)
  __shared__ unsigned long long smp[8][4][7];
  const int tid = threadIdx.x;
  const int lane = tid & 63;
  const int n = blockIdx.x >> 5;          // 32 blocks per sample
  const int k0 = (blockIdx.x & 31) * 8;

  if (blockIdx.x == 0 && tid == 0) atomicExch(counter, 0u);  // coherent zero
  if (tid < 64) {  // zero the guard words (idx 0 and 5)
    smp[tid >> 3][(tid >> 1) & 3][(tid & 1) * 5] = 0ull;
  }
  {
    const int r = tid >> 7;               // row 0..7
    const int h = (tid >> 6) & 1;         // 64-bit word half
    const int j1 = h * 64 + lane;
    const int rowOff = (n * Hh + k0 + r) * Ww;
    const int t1 = tgt[rowOff + j1];
    const int t2 = tgt[rowOff + j1 + 128];
#pragma unroll
    for (int c = 0; c < Cc; ++c) {
      const unsigned long long m1 = __ballot(t1 == c);
      const unsigned long long m2 = __ballot(t2 == c);
      if (lane == 0) {
        smp[r][c][1 + h] = m1;
        smp[r][c][3 + h] = m2;
      }
    }
  }
  __syncthreads();

  const int r = tid >> 7;                 // row 0..7
  const int jj = tid & 127;
  const int rowOut = (n * Hh + k0 + r) * Ww;
#pragma unroll
  for (int half = 0; half < 2; ++half) {
    const int j = jj + half * 128;
    const int S = j + 32;                 // padded bitspace: orig bit x = 64+x
    const int word = S >> 6;              // 0..4
    const int sh = S & 63;
    int d[4];
#pragma unroll
    for (int c = 0; c < Cc; ++c) {
      const unsigned long long* M = smp[r][c];
      const unsigned long long lo = M[word];
      const unsigned long long hi = M[word + 1];
      const unsigned long long win =
          sh ? ((lo >> sh) | (hi << (64 - sh))) : lo;  // bits [j-32, j+31]
      const unsigned long long ml = win & 0x1FFFFFFFFull;  // <= pixel (bit 32)
      const unsigned long long mr = win >> 32;             // >= pixel
      int dd;
      if (ml | mr) {
        const int dl = ml ? (__builtin_clzll(ml) - 31) : 512;
        const int dr = mr ? (int)__builtin_ctzll(mr) : 512;
        dd = min(dl, dr);
      } else {
        // exact rare fallback: full 4-word scan both directions
        int dl = 512, dr = 512;
#pragma unroll
        for (int w = 3; w >= 0; --w) {
          if (w * 64 <= j) {
            unsigned long long m = M[1 + w];
            if (w == (j >> 6)) {
              const int r6 = j & 63;
              m &= (r6 == 63) ? ~0ull : ((1ull << (r6 + 1)) - 1ull);
            }
            if (m && dl == 512) dl = j - (w * 64 + 63 - __builtin_clzll(m));
          }
        }
#pragma unroll
        for (int w = 0; w < 4; ++w) {
          if (w * 64 + 63 >= j) {
            unsigned long long m = M[1 + w];
            if (w == (j >> 6)) m &= ~((1ull << (j & 63)) - 1ull);
            if (m && dr == 512) dr = w * 64 + (int)__builtin_ctzll(m) - j;
          }
        }
        dd = min(min(dl, dr), 512);
      }
      d[c] = dd;
    }
    ushort4 out;
    out.x = (unsigned short)d[0];
    out.y = (unsigned short)d[1];
    out.z = (unsigned short)d[2];
    out.w = (unsigned short)d[3];
    g[rowOut + j] = out;                  // coalesced: lanes = consecutive j
  }
}

// ---------------------------------------------------------------------------
// Kernel B (fused, LDS-staged): tile 4i x 64j, 256 thr, one pixel per thread.
// Stage 20 rows of g^2 in LDS (uint4, sentinel outside image; 20KB -> 8
// blocks/CU = 32 waves/CU). Window taps come from ds_read_b128 (pipelined,
// no L2 round-trips); per thread only 9 independent global loads. Exact >81
// full-column global rescan fallback. Softmax + loss + deterministic
// ticketed reduction as before.
// ---------------------------------------------------------------------------
__global__ __launch_bounds__(256) void fused_kernel(
    const float* __restrict__ in, const ushort4* __restrict__ g,
    float* __restrict__ partials, unsigned* __restrict__ counter,
    float* __restrict__ out) {
  __shared__ uint4 s2[20][64];            // 20,480 B
  __shared__ float s_w[4];
  __shared__ int s_flag;
  __shared__ float s_red[256];
  const int bid = blockIdx.x;   // 8 n * 64 i-tiles * 4 j-tiles = 2048
  const int n = bid >> 8;
  const int it = (bid >> 2) & 63;
  const int jt = bid & 3;
  const int tid = threadIdx.x;
  const int jj = tid & 63;
  const int j = jt * 64 + jj;
  const int il = tid >> 6;                // wave-uniform
  const int i0 = it * 4;
  const int i = i0 + il;

  const int gBase = n * (Hh * Ww) + j;    // ushort4 units
  // stage g^2 rows [i0-8, i0+11]; slot r <-> global row k = i0-8+r
#pragma unroll
  for (int q = 0; q < 5; ++q) {
    const int r = il + q * 4;             // wave-uniform
    const int k = i0 - 8 + r;
    uint4 sq;
    if (k >= 0 && k < Hh) {               // wave-uniform branch
      const ushort4 gv = g[gBase + k * Ww];  // coalesced 512B
      sq.x = (unsigned)gv.x * (unsigned)gv.x;
      sq.y = (unsigned)gv.y * (unsigned)gv.y;
      sq.z = (unsigned)gv.z * (unsigned)gv.z;
      sq.w = (unsigned)gv.w * (unsigned)gv.w;
    } else {
      sq.x = sq.y = sq.z = sq.w = BIGD;   // sentinel: never wins the min
    }
    s2[r][jj] = sq;                       // conflict-free b128 write
  }
  // independent logit loads (one round-trip, overlap with LDS fill)
  const long cs = (long)Hh * Ww;          // class stride in floats
  const float* lp = in + ((long)(n * Cc) * Hh + i) * Ww + j;
  const float x0 = lp[0];
  const float x1 = lp[cs];
  const float x2 = lp[2 * cs];
  const float x3 = lp[3 * cs];
  __syncthreads();

  int d0 = 0x7fffffff, d1 = 0x7fffffff, d2 = 0x7fffffff, d3 = 0x7fffffff;
#pragma unroll
  for (int kq = 0; kq <= 16; ++kq) {
    const uint4 gq = s2[il + kq][jj];     // conflict-free b128 read
    const int dd = (8 - kq) * (8 - kq);   // compile-time constant
    d0 = min(d0, (int)gq.x + dd);
    d1 = min(d1, (int)gq.y + dd);
    d2 = min(d2, (int)gq.z + dd);
    d3 = min(d3, (int)gq.w + dd);
  }
  // Exactness: excluded k have (i-k)^2 >= 81; if min <= 81 window is exact.
  if (__any(max(max(d0, d1), max(d2, d3)) > 81)) {  // rare exact fallback
    const ushort4* gp = g + gBase;
    for (int k = 0; k < Hh; ++k) {
      const ushort4 gv = gp[k * Ww];
      const int di = i - k;
      const int dd = di * di;
      d0 = min(d0, (int)gv.x * (int)gv.x + dd);
      d1 = min(d1, (int)gv.y * (int)gv.y + dd);
      d2 = min(d2, (int)gv.z * (int)gv.z + dd);
      d3 = min(d3, (int)gv.w * (int)gv.w + dd);
    }
  }

  // exact conversions: all d2 < 2^24
  const float f0 = (float)d0, f1 = (float)d1;
  const float f2 = (float)d2, f3 = (float)d3;

  const float mx = fmaxf(fmaxf(x0, x1), fmaxf(x2, x3));
  const float e0 = expf(x0 - mx), e1 = expf(x1 - mx);
  const float e2 = expf(x2 - mx), e3 = expf(x3 - mx);
  const float rs = 1.0f / (e0 + e1 + e2 + e3);
  const float p0 = e0 * rs, p1 = e1 * rs, p2 = e2 * rs, p3 = e3 * rs;
  // own-class d2 is exactly 0 (k=i, g=0); exclude it for dbar
  const int q0 = (d0 == 0) ? 0x7fffffff : d0;
  const int q1 = (d1 == 0) ? 0x7fffffff : d1;
  const int q2 = (d2 == 0) ? 0x7fffffff : d2;
  const int q3 = (d3 == 0) ? 0x7fffffff : d3;
  const float dbar = (float)min(min(q0, q1), min(q2, q3));
  const float pt = (d0 == 0) ? p0 : (d1 == 0) ? p1 : (d2 == 0) ? p2 : p3;
  float contrib = pt * sqrtf(dbar) -
                  (p0 * sqrtf(f0) + p1 * sqrtf(f1) +
                   p2 * sqrtf(f2) + p3 * sqrtf(f3));

  // block reduction (deterministic fixed order)
#pragma unroll
  for (int off = 32; off > 0; off >>= 1) contrib += __shfl_down(contrib, off);
  if ((tid & 63) == 0) s_w[tid >> 6] = contrib;
  __syncthreads();
  if (tid == 0) {
    const float v = (s_w[0] + s_w[1]) + (s_w[2] + s_w[3]);
    partials[bid] = v;
    __threadfence();                      // device-scope: publish partial
    const unsigned t = atomicAdd(counter, 1u);
    s_flag = (t == (unsigned)(gridDim.x - 1));
  }
  __syncthreads();
  if (s_flag) {                           // last block: final reduction
    // 8 independent coherent (atomic) reads -> pipelined, then fixed-order sum
    float v[8];
#pragma unroll
    for (int q = 0; q < 8; ++q)
      v[q] = atomicAdd(&partials[tid + q * 256], 0.0f);
    float a = 0.0f;
#pragma unroll
    for (int q = 0; q < 8; ++q) a += v[q];
    s_red[tid] = a;
    __syncthreads();
    for (int st = 128; st > 0; st >>= 1) {
      if (tid < st) s_red[tid] += s_red[tid + st];
      __syncthreads();
    }
    if (tid == 0)
      out[0] = s_red[0] / (float)(Cc * Nn) / (65536.0f + 1e-6f);
  }
}

extern "C" void kernel_launch(void* const* d_in, const int* in_sizes, int n_in,
                              void* d_out, int out_size, void* d_ws, size_t ws_size,
                              hipStream_t stream) {
  const float* input = (const float*)d_in[0];   // [8,4,256,256] fp32 logits
  const int* target = (const int*)d_in[1];      // [8,256,256] int32
  float* out = (float*)d_out;                   // scalar fp32
  char* ws = (char*)d_ws;
  ushort4* g = (ushort4*)(ws + OFF_G);
  float* partials = (float*)(ws + OFF_PART);
  unsigned* counter = (unsigned*)(ws + OFF_CNT);

  edt_rows_kernel<<<dim3((Nn * Hh) / 8), dim3(1024), 0, stream>>>(target, g,
                                                                  counter);
  fused_kernel<<<dim3(2048), dim3(256), 0, stream>>>(input, g, partials,
                                                     counter, out);
}

// Round 7
// 20.927 us; speedup vs baseline: 2.6116x; 2.6116x over previous
//
#include <hip/hip_runtime.h>

#define Nn 8
#define Cc 4
#define Hh 256
#define Ww 256
#define BIGD 0x20000000

// Workspace layout (bytes):
//   g       : [n][k][j] ushort4 (per-class row distance, <=512) -> 4,194,304
//   partials: [2048] float                                      ->     8,192
#define OFF_G    0
#define OFF_PART 4194304

// ---------------------------------------------------------------------------
// Kernel A: exact per-row 1-D nearest-class distance via 256-bit class masks.
// (unchanged; ~2us measured by subtraction in R5)
// ---------------------------------------------------------------------------
__global__ __launch_bounds__(1024) void edt_rows_kernel(
    const int* __restrict__ tgt, ushort4* __restrict__ g) {
  // [row][class][guard0, w0..w3, guard5, pad] ; stride 7 -> <=2-way (free)
  __shared__ unsigned long long smp[8][4][7];
  const int tid = threadIdx.x;
  const int lane = tid & 63;
  const int n = blockIdx.x >> 5;          // 32 blocks per sample
  const int k0 = (blockIdx.x & 31) * 8;

  if (tid < 64) {  // zero the guard words (idx 0 and 5)
    smp[tid >> 3][(tid >> 1) & 3][(tid & 1) * 5] = 0ull;
  }
  {
    const int r = tid >> 7;               // row 0..7
    const int h = (tid >> 6) & 1;         // 64-bit word half
    const int j1 = h * 64 + lane;
    const int rowOff = (n * Hh + k0 + r) * Ww;
    const int t1 = tgt[rowOff + j1];
    const int t2 = tgt[rowOff + j1 + 128];
#pragma unroll
    for (int c = 0; c < Cc; ++c) {
      const unsigned long long m1 = __ballot(t1 == c);
      const unsigned long long m2 = __ballot(t2 == c);
      if (lane == 0) {
        smp[r][c][1 + h] = m1;
        smp[r][c][3 + h] = m2;
      }
    }
  }
  __syncthreads();

  const int r = tid >> 7;                 // row 0..7
  const int jj = tid & 127;
  const int rowOut = (n * Hh + k0 + r) * Ww;
#pragma unroll
  for (int half = 0; half < 2; ++half) {
    const int j = jj + half * 128;
    const int S = j + 32;                 // padded bitspace: orig bit x = 64+x
    const int word = S >> 6;              // 0..4
    const int sh = S & 63;
    int d[4];
#pragma unroll
    for (int c = 0; c < Cc; ++c) {
      const unsigned long long* M = smp[r][c];
      const unsigned long long lo = M[word];
      const unsigned long long hi = M[word + 1];
      const unsigned long long win =
          sh ? ((lo >> sh) | (hi << (64 - sh))) : lo;  // bits [j-32, j+31]
      const unsigned long long ml = win & 0x1FFFFFFFFull;  // <= pixel (bit 32)
      const unsigned long long mr = win >> 32;             // >= pixel
      int dd;
      if (ml | mr) {
        const int dl = ml ? (__builtin_clzll(ml) - 31) : 512;
        const int dr = mr ? (int)__builtin_ctzll(mr) : 512;
        dd = min(dl, dr);
      } else {
        // exact rare fallback: full 4-word scan both directions
        int dl = 512, dr = 512;
#pragma unroll
        for (int w = 3; w >= 0; --w) {
          if (w * 64 <= j) {
            unsigned long long m = M[1 + w];
            if (w == (j >> 6)) {
              const int r6 = j & 63;
              m &= (r6 == 63) ? ~0ull : ((1ull << (r6 + 1)) - 1ull);
            }
            if (m && dl == 512) dl = j - (w * 64 + 63 - __builtin_clzll(m));
          }
        }
#pragma unroll
        for (int w = 0; w < 4; ++w) {
          if (w * 64 + 63 >= j) {
            unsigned long long m = M[1 + w];
            if (w == (j >> 6)) m &= ~((1ull << (j & 63)) - 1ull);
            if (m && dr == 512) dr = w * 64 + (int)__builtin_ctzll(m) - j;
          }
        }
        dd = min(min(dl, dr), 512);
      }
      d[c] = dd;
    }
    ushort4 out;
    out.x = (unsigned short)d[0];
    out.y = (unsigned short)d[1];
    out.z = (unsigned short)d[2];
    out.w = (unsigned short)d[3];
    g[rowOut + j] = out;                  // coalesced: lanes = consecutive j
  }
}

// ---------------------------------------------------------------------------
// Kernel B (fused, LDS-staged): tile 4i x 64j, 256 thr, one pixel per thread.
// Identical to R6 EXCEPT: no threadfence, no ticket atomic — ends with one
// plain partials[bid] store. (This round's single variable: the device-scope
// reduction tail, implicated by the ~55 cy/block scaling across R4/R5/R6.)
// ---------------------------------------------------------------------------
__global__ __launch_bounds__(256) void fused_kernel(
    const float* __restrict__ in, const ushort4* __restrict__ g,
    float* __restrict__ partials) {
  __shared__ uint4 s2[20][64];            // 20,480 B
  __shared__ float s_w[4];
  const int bid = blockIdx.x;   // 8 n * 64 i-tiles * 4 j-tiles = 2048
  const int n = bid >> 8;
  const int it = (bid >> 2) & 63;
  const int jt = bid & 3;
  const int tid = threadIdx.x;
  const int jj = tid & 63;
  const int j = jt * 64 + jj;
  const int il = tid >> 6;                // wave-uniform
  const int i0 = it * 4;
  const int i = i0 + il;

  const int gBase = n * (Hh * Ww) + j;    // ushort4 units
  // stage g^2 rows [i0-8, i0+11]; slot r <-> global row k = i0-8+r
#pragma unroll
  for (int q = 0; q < 5; ++q) {
    const int r = il + q * 4;             // wave-uniform
    const int k = i0 - 8 + r;
    uint4 sq;
    if (k >= 0 && k < Hh) {               // wave-uniform branch
      const ushort4 gv = g[gBase + k * Ww];  // coalesced 512B
      sq.x = (unsigned)gv.x * (unsigned)gv.x;
      sq.y = (unsigned)gv.y * (unsigned)gv.y;
      sq.z = (unsigned)gv.z * (unsigned)gv.z;
      sq.w = (unsigned)gv.w * (unsigned)gv.w;
    } else {
      sq.x = sq.y = sq.z = sq.w = BIGD;   // sentinel: never wins the min
    }
    s2[r][jj] = sq;                       // conflict-free b128 write
  }
  // independent logit loads (one round-trip, overlap with LDS fill)
  const long cs = (long)Hh * Ww;          // class stride in floats
  const float* lp = in + ((long)(n * Cc) * Hh + i) * Ww + j;
  const float x0 = lp[0];
  const float x1 = lp[cs];
  const float x2 = lp[2 * cs];
  const float x3 = lp[3 * cs];
  __syncthreads();

  int d0 = 0x7fffffff, d1 = 0x7fffffff, d2 = 0x7fffffff, d3 = 0x7fffffff;
#pragma unroll
  for (int kq = 0; kq <= 16; ++kq) {
    const uint4 gq = s2[il + kq][jj];     // conflict-free b128 read
    const int dd = (8 - kq) * (8 - kq);   // compile-time constant
    d0 = min(d0, (int)gq.x + dd);
    d1 = min(d1, (int)gq.y + dd);
    d2 = min(d2, (int)gq.z + dd);
    d3 = min(d3, (int)gq.w + dd);
  }
  // Exactness: excluded k have (i-k)^2 >= 81; if min <= 81 window is exact.
  if (__any(max(max(d0, d1), max(d2, d3)) > 81)) {  // rare exact fallback
    const ushort4* gp = g + gBase;
    for (int k = 0; k < Hh; ++k) {
      const ushort4 gv = gp[k * Ww];
      const int di = i - k;
      const int dd = di * di;
      d0 = min(d0, (int)gv.x * (int)gv.x + dd);
      d1 = min(d1, (int)gv.y * (int)gv.y + dd);
      d2 = min(d2, (int)gv.z * (int)gv.z + dd);
      d3 = min(d3, (int)gv.w * (int)gv.w + dd);
    }
  }

  // exact conversions: all d2 < 2^24
  const float f0 = (float)d0, f1 = (float)d1;
  const float f2 = (float)d2, f3 = (float)d3;

  const float mx = fmaxf(fmaxf(x0, x1), fmaxf(x2, x3));
  const float e0 = expf(x0 - mx), e1 = expf(x1 - mx);
  const float e2 = expf(x2 - mx), e3 = expf(x3 - mx);
  const float rs = 1.0f / (e0 + e1 + e2 + e3);
  const float p0 = e0 * rs, p1 = e1 * rs, p2 = e2 * rs, p3 = e3 * rs;
  // own-class d2 is exactly 0 (k=i, g=0); exclude it for dbar
  const int q0 = (d0 == 0) ? 0x7fffffff : d0;
  const int q1 = (d1 == 0) ? 0x7fffffff : d1;
  const int q2 = (d2 == 0) ? 0x7fffffff : d2;
  const int q3 = (d3 == 0) ? 0x7fffffff : d3;
  const float dbar = (float)min(min(q0, q1), min(q2, q3));
  const float pt = (d0 == 0) ? p0 : (d1 == 0) ? p1 : (d2 == 0) ? p2 : p3;
  float contrib = pt * sqrtf(dbar) -
                  (p0 * sqrtf(f0) + p1 * sqrtf(f1) +
                   p2 * sqrtf(f2) + p3 * sqrtf(f3));

  // block reduction (deterministic fixed order)
#pragma unroll
  for (int off = 32; off > 0; off >>= 1) contrib += __shfl_down(contrib, off);
  if ((tid & 63) == 0) s_w[tid >> 6] = contrib;
  __syncthreads();
  if (tid == 0) {
    partials[bid] = (s_w[0] + s_w[1]) + (s_w[2] + s_w[3]);  // plain store
  }
}

// ---------------------------------------------------------------------------
// Kernel C: deterministic final reduction + scaling (1 block; visibility via
// kernel-boundary acquire/release on the stream — no fences needed)
// ---------------------------------------------------------------------------
__global__ __launch_bounds__(256) void finalize_kernel(
    const float* __restrict__ partials, float* __restrict__ out) {
  __shared__ float s_red[256];
  const int tid = threadIdx.x;
  float v[8];
#pragma unroll
  for (int q = 0; q < 8; ++q) v[q] = partials[tid + q * 256];  // independent
  float a = 0.0f;
#pragma unroll
  for (int q = 0; q < 8; ++q) a += v[q];
  s_red[tid] = a;
  __syncthreads();
  for (int st = 128; st > 0; st >>= 1) {
    if (tid < st) s_red[tid] += s_red[tid + st];
    __syncthreads();
  }
  if (tid == 0)
    out[0] = s_red[0] / (float)(Cc * Nn) / (65536.0f + 1e-6f);
}

extern "C" void kernel_launch(void* const* d_in, const int* in_sizes, int n_in,
                              void* d_out, int out_size, void* d_ws, size_t ws_size,
                              hipStream_t stream) {
  const float* input = (const float*)d_in[0];   // [8,4,256,256] fp32 logits
  const int* target = (const int*)d_in[1];      // [8,256,256] int32
  float* out = (float*)d_out;                   // scalar fp32
  char* ws = (char*)d_ws;
  ushort4* g = (ushort4*)(ws + OFF_G);
  float* partials = (float*)(ws + OFF_PART);

  edt_rows_kernel<<<dim3((Nn * Hh) / 8), dim3(1024), 0, stream>>>(target, g);
  fused_kernel<<<dim3(2048), dim3(256), 0, stream>>>(input, g, partials);
  finalize_kernel<<<dim3(1), dim3(256), 0, stream>>>(partials, out);
}

// Round 8
// 20.652 us; speedup vs baseline: 2.6463x; 1.0133x over previous
//
#include <hip/hip_runtime.h>

#define Nn 8
#define Cc 4
#define Hh 256
#define Ww 256

typedef unsigned short u16;
typedef u16 u16x4 __attribute__((ext_vector_type(4)));

// Workspace layout (bytes):
//   g       : [n][k][j] ushort4 (per-class row distance, <=512) -> 4,194,304
//   partials: [2048] float                                      ->     8,192
#define OFF_G    0
#define OFF_PART 4194304

// ---------------------------------------------------------------------------
// Kernel A: exact per-row 1-D nearest-class distance via 256-bit class masks.
// (byte-identical to R7 — this round's single variable is kernel B)
// ---------------------------------------------------------------------------
__global__ __launch_bounds__(1024) void edt_rows_kernel(
    const int* __restrict__ tgt, ushort4* __restrict__ g) {
  // [row][class][guard0, w0..w3, guard5, pad] ; stride 7 -> <=2-way (free)
  __shared__ unsigned long long smp[8][4][7];
  const int tid = threadIdx.x;
  const int lane = tid & 63;
  const int n = blockIdx.x >> 5;          // 32 blocks per sample
  const int k0 = (blockIdx.x & 31) * 8;

  if (tid < 64) {  // zero the guard words (idx 0 and 5)
    smp[tid >> 3][(tid >> 1) & 3][(tid & 1) * 5] = 0ull;
  }
  {
    const int r = tid >> 7;               // row 0..7
    const int h = (tid >> 6) & 1;         // 64-bit word half
    const int j1 = h * 64 + lane;
    const int rowOff = (n * Hh + k0 + r) * Ww;
    const int t1 = tgt[rowOff + j1];
    const int t2 = tgt[rowOff + j1 + 128];
#pragma unroll
    for (int c = 0; c < Cc; ++c) {
      const unsigned long long m1 = __ballot(t1 == c);
      const unsigned long long m2 = __ballot(t2 == c);
      if (lane == 0) {
        smp[r][c][1 + h] = m1;
        smp[r][c][3 + h] = m2;
      }
    }
  }
  __syncthreads();

  const int r = tid >> 7;                 // row 0..7
  const int jj = tid & 127;
  const int rowOut = (n * Hh + k0 + r) * Ww;
#pragma unroll
  for (int half = 0; half < 2; ++half) {
    const int j = jj + half * 128;
    const int S = j + 32;                 // padded bitspace: orig bit x = 64+x
    const int word = S >> 6;              // 0..4
    const int sh = S & 63;
    int d[4];
#pragma unroll
    for (int c = 0; c < Cc; ++c) {
      const unsigned long long* M = smp[r][c];
      const unsigned long long lo = M[word];
      const unsigned long long hi = M[word + 1];
      const unsigned long long win =
          sh ? ((lo >> sh) | (hi << (64 - sh))) : lo;  // bits [j-32, j+31]
      const unsigned long long ml = win & 0x1FFFFFFFFull;  // <= pixel (bit 32)
      const unsigned long long mr = win >> 32;             // >= pixel
      int dd;
      if (ml | mr) {
        const int dl = ml ? (__builtin_clzll(ml) - 31) : 512;
        const int dr = mr ? (int)__builtin_ctzll(mr) : 512;
        dd = min(dl, dr);
      } else {
        // exact rare fallback: full 4-word scan both directions
        int dl = 512, dr = 512;
#pragma unroll
        for (int w = 3; w >= 0; --w) {
          if (w * 64 <= j) {
            unsigned long long m = M[1 + w];
            if (w == (j >> 6)) {
              const int r6 = j & 63;
              m &= (r6 == 63) ? ~0ull : ((1ull << (r6 + 1)) - 1ull);
            }
            if (m && dl == 512) dl = j - (w * 64 + 63 - __builtin_clzll(m));
          }
        }
#pragma unroll
        for (int w = 0; w < 4; ++w) {
          if (w * 64 + 63 >= j) {
            unsigned long long m = M[1 + w];
            if (w == (j >> 6)) m &= ~((1ull << (j & 63)) - 1ull);
            if (m && dr == 512) dr = w * 64 + (int)__builtin_ctzll(m) - j;
          }
        }
        dd = min(min(dl, dr), 512);
      }
      d[c] = dd;
    }
    ushort4 out;
    out.x = (unsigned short)d[0];
    out.y = (unsigned short)d[1];
    out.z = (unsigned short)d[2];
    out.w = (unsigned short)d[3];
    g[rowOut + j] = out;                  // coalesced: lanes = consecutive j
  }
}

// ---------------------------------------------------------------------------
// Kernel B (fused): tile 4i x 64j, one pixel per thread.
// This round: (a) logit loads AFTER the barrier (overlap window compute, no
// vmcnt(0) drain of cold HBM loads at the barrier); (b) packed-u16 window:
// stage sat-u16 g^2 (clamp g to 255 -> g^2<=65025; sentinel 0xFF00; max
// stored+dd = 65089 < 65536, no wrap). Saturation only alters values >= 65025
// > 81, so: computed min <= 81  <=>  true min <= 81 (exact, window wins);
// computed min > 81 -> exact fallback which REINITIALIZES d (saturated
// carries could underestimate a > 65025 true min) and rescans global g in
// full int precision. (c) __expf softmax.
// ---------------------------------------------------------------------------
__global__ __launch_bounds__(256) void fused_kernel(
    const float* __restrict__ in, const ushort4* __restrict__ g,
    float* __restrict__ partials) {
  __shared__ u16x4 s2[20][64];            // 10,240 B
  __shared__ float s_w[4];
  const int bid = blockIdx.x;   // 8 n * 64 i-tiles * 4 j-tiles = 2048
  const int n = bid >> 8;
  const int it = (bid >> 2) & 63;
  const int jt = bid & 3;
  const int tid = threadIdx.x;
  const int jj = tid & 63;
  const int j = jt * 64 + jj;
  const int il = tid >> 6;                // wave-uniform
  const int i0 = it * 4;
  const int i = i0 + il;

  const int gBase = n * (Hh * Ww) + j;    // ushort4 units
  // stage sat-u16 g^2 rows [i0-8, i0+11]; slot r <-> global row k = i0-8+r
  const u16x4 k255 = {255, 255, 255, 255};
  const u16x4 sent = {0xFF00, 0xFF00, 0xFF00, 0xFF00};
#pragma unroll
  for (int q = 0; q < 5; ++q) {
    const int r = il + q * 4;             // wave-uniform
    const int k = i0 - 8 + r;
    u16x4 sq = sent;
    if (k >= 0 && k < Hh) {               // wave-uniform branch
      const ushort4 gv = g[gBase + k * Ww];  // coalesced
      u16x4 c = {gv.x, gv.y, gv.z, gv.w};
      c = __builtin_elementwise_min(c, k255);
      sq = c * c;                         // v_pk_mul_lo_u16, <= 65025
    }
    s2[r][jj] = sq;                       // conflict-free b64 write
  }
  __syncthreads();

  u16x4 acc = {0xFFFF, 0xFFFF, 0xFFFF, 0xFFFF};
#pragma unroll
  for (int kq = 0; kq <= 16; ++kq) {
    const int dd = (8 - kq) * (8 - kq);   // compile-time constant
    const u16x4 ddv = {(u16)dd, (u16)dd, (u16)dd, (u16)dd};
    const u16x4 t = s2[il + kq][jj] + ddv;   // b64 read + 2x pk_add
    acc = __builtin_elementwise_min(acc, t); // 2x pk_min
  }
  int d0 = acc.x, d1 = acc.y, d2 = acc.z, d3 = acc.w;

  // independent logit loads — in flight during the fallback check / softmax
  const long cs = (long)Hh * Ww;          // class stride in floats
  const float* lp = in + ((long)(n * Cc) * Hh + i) * Ww + j;
  const float x0 = lp[0];
  const float x1 = lp[cs];
  const float x2 = lp[2 * cs];
  const float x3 = lp[3 * cs];

  // Exactness: excluded k have (i-k)^2 >= 81; if min <= 81 window is exact.
  if (__any(max(max(d0, d1), max(d2, d3)) > 81)) {  // rare exact fallback
    d0 = 0x7fffffff; d1 = 0x7fffffff; d2 = 0x7fffffff; d3 = 0x7fffffff;
    const ushort4* gp = g + gBase;
    for (int k = 0; k < Hh; ++k) {
      const ushort4 gv = gp[k * Ww];
      const int di = i - k;
      const int dd = di * di;
      d0 = min(d0, (int)gv.x * (int)gv.x + dd);
      d1 = min(d1, (int)gv.y * (int)gv.y + dd);
      d2 = min(d2, (int)gv.z * (int)gv.z + dd);
      d3 = min(d3, (int)gv.w * (int)gv.w + dd);
    }
  }

  // exact conversions: all d2 < 2^24
  const float f0 = (float)d0, f1 = (float)d1;
  const float f2 = (float)d2, f3 = (float)d3;

  const float mx = fmaxf(fmaxf(x0, x1), fmaxf(x2, x3));
  const float e0 = __expf(x0 - mx), e1 = __expf(x1 - mx);
  const float e2 = __expf(x2 - mx), e3 = __expf(x3 - mx);
  const float rs = 1.0f / (e0 + e1 + e2 + e3);
  const float p0 = e0 * rs, p1 = e1 * rs, p2 = e2 * rs, p3 = e3 * rs;
  // own-class d2 is exactly 0 (k=i, g=0); exclude it for dbar
  const int q0 = (d0 == 0) ? 0x7fffffff : d0;
  const int q1 = (d1 == 0) ? 0x7fffffff : d1;
  const int q2 = (d2 == 0) ? 0x7fffffff : d2;
  const int q3 = (d3 == 0) ? 0x7fffffff : d3;
  const float dbar = (float)min(min(q0, q1), min(q2, q3));
  const float pt = (d0 == 0) ? p0 : (d1 == 0) ? p1 : (d2 == 0) ? p2 : p3;
  float contrib = pt * sqrtf(dbar) -
                  (p0 * sqrtf(f0) + p1 * sqrtf(f1) +
                   p2 * sqrtf(f2) + p3 * sqrtf(f3));

  // block reduction (deterministic fixed order)
#pragma unroll
  for (int off = 32; off > 0; off >>= 1) contrib += __shfl_down(contrib, off);
  if ((tid & 63) == 0) s_w[tid >> 6] = contrib;
  __syncthreads();
  if (tid == 0) {
    partials[bid] = (s_w[0] + s_w[1]) + (s_w[2] + s_w[3]);  // plain store
  }
}

// ---------------------------------------------------------------------------
// Kernel C: deterministic final reduction + scaling (byte-identical to R7)
// ---------------------------------------------------------------------------
__global__ __launch_bounds__(256) void finalize_kernel(
    const float* __restrict__ partials, float* __restrict__ out) {
  __shared__ float s_red[256];
  const int tid = threadIdx.x;
  float v[8];
#pragma unroll
  for (int q = 0; q < 8; ++q) v[q] = partials[tid + q * 256];  // independent
  float a = 0.0f;
#pragma unroll
  for (int q = 0; q < 8; ++q) a += v[q];
  s_red[tid] = a;
  __syncthreads();
  for (int st = 128; st > 0; st >>= 1) {
    if (tid < st) s_red[tid] += s_red[tid + st];
    __syncthreads();
  }
  if (tid == 0)
    out[0] = s_red[0] / (float)(Cc * Nn) / (65536.0f + 1e-6f);
}

extern "C" void kernel_launch(void* const* d_in, const int* in_sizes, int n_in,
                              void* d_out, int out_size, void* d_ws, size_t ws_size,
                              hipStream_t stream) {
  const float* input = (const float*)d_in[0];   // [8,4,256,256] fp32 logits
  const int* target = (const int*)d_in[1];      // [8,256,256] int32
  float* out = (float*)d_out;                   // scalar fp32
  char* ws = (char*)d_ws;
  ushort4* g = (ushort4*)(ws + OFF_G);
  float* partials = (float*)(ws + OFF_PART);

  edt_rows_kernel<<<dim3((Nn * Hh) / 8), dim3(1024), 0, stream>>>(target, g);
  fused_kernel<<<dim3(2048), dim3(256), 0, stream>>>(input, g, partials);
  finalize_kernel<<<dim3(1), dim3(256), 0, stream>>>(partials, out);
}

// Round 9
// 20.145 us; speedup vs baseline: 2.7130x; 1.0252x over previous
//
#include <hip/hip_runtime.h>

#define Nn 8
#define Cc 4
#define Hh 256
#define Ww 256

typedef unsigned short u16;
typedef u16 u16x4 __attribute__((ext_vector_type(4)));
typedef unsigned long long u64;

// Workspace layout (bytes): partials only
#define OFF_PART 0

// ---------------------------------------------------------------------------
// Merged kernel: one block = 16i x 64j tile. Per block:
//  1. issue 16 logit loads (4 px * 4 classes) — in flight through phases 2-3
//  2. build 256-bit class masks for the 32 g-rows (8-row halo) via __ballot
//  3. per (row, j): exact row distance g via funnel/clz window (+ exact
//     4-word fallback), clamp 255, square -> sat-u16 g^2 staged in LDS
//  4. sliding 20-read column window (radius 8) in packed u16
//  5. exactness: window min <= 81 is provably exact; else rare (P~1e-18)
//     EXACT brute-force scan of the sample's target
//  6. softmax + boundary-loss + deterministic block reduction
// ---------------------------------------------------------------------------
__global__ __launch_bounds__(256) void merged_kernel(
    const int* __restrict__ tgt, const float* __restrict__ in,
    float* __restrict__ partials) {
  __shared__ u64 smp[32][4][6];   // [row][class][guard,w0..w3,guard] = 6 KB
  __shared__ u16x4 s2[32][64];    // sat g^2, row r <-> k = i0-8+r   = 16 KB
  __shared__ float s_w[4];
  const int bid = blockIdx.x;     // n*64 + it*4 + jt  (8*16*4 = 512)
  const int n = bid >> 6;
  const int it = (bid >> 2) & 15;
  const int jt = bid & 3;
  const int i0 = it * 16, j0 = jt * 64;
  const int tid = threadIdx.x;
  const int lane = tid & 63;
  const int w = tid >> 6;         // wave id 0..3 (== il)
  const int jj = tid & 63;
  const int j = j0 + jj;

  // ---- 1. logit loads up front (independent; hidden under phases 2-3) ----
  const long cs = (long)Hh * Ww;
  const float* lp = in + ((long)(n * Cc) * Hh + (i0 + w * 4)) * Ww + j;
  float x[4][4];                  // [m][c] — all indices compile-time
#pragma unroll
  for (int c = 0; c < 4; ++c)
#pragma unroll
    for (int m = 0; m < 4; ++m) x[m][c] = lp[c * cs + m * Ww];

  // ---- guards ----
  {
    const int r = tid >> 3, c = (tid >> 1) & 3, g01 = (tid & 1) * 5;
    smp[r][c][g01] = 0ull;        // 256 threads cover 32*4*2 exactly
  }

  // ---- 2. mask build: wave w -> rows w*8 .. w*8+7 ----
#pragma unroll
  for (int rr = 0; rr < 8; ++rr) {
    const int r = w * 8 + rr;
    const int k = i0 - 8 + r;
    if (k >= 0 && k < Hh) {       // wave-uniform
      const int rowOff = (n * Hh + k) * Ww;
      const int t0 = tgt[rowOff + lane];
      const int t1 = tgt[rowOff + lane + 64];
      const int t2 = tgt[rowOff + lane + 128];
      const int t3 = tgt[rowOff + lane + 192];
#pragma unroll
      for (int c = 0; c < Cc; ++c) {
        const u64 m0 = __ballot(t0 == c);
        const u64 m1 = __ballot(t1 == c);
        const u64 m2 = __ballot(t2 == c);
        const u64 m3 = __ballot(t3 == c);
        if (lane == 0) {
          smp[r][c][1] = m0; smp[r][c][2] = m1;
          smp[r][c][3] = m2; smp[r][c][4] = m3;
        }
      }
    }
  }
  __syncthreads();

  // ---- 3. g^2 compute: thread (rq=w, jj) handles rows rq*8+q ----
  const u16 SENT = 0xFE00;        // 65024; +dd(<=64) = 65088 < 65536 no wrap
#pragma unroll
  for (int q = 0; q < 8; ++q) {
    const int r = w * 8 + q;
    const int k = i0 - 8 + r;
    u16x4 sq = {SENT, SENT, SENT, SENT};
    if (k >= 0 && k < Hh) {       // wave-uniform
      const int S = j + 32;       // abs bitspace: orig bit x at 64+x
      const int word = S >> 6;    // 0..4
      const int sh = S & 63;
      u16 dv[4];
#pragma unroll
      for (int c = 0; c < Cc; ++c) {
        const u64* M = smp[r][c];
        const u64 lo = M[word];
        const u64 hi = M[word + 1];
        const u64 win = sh ? ((lo >> sh) | (hi << (64 - sh))) : lo;
        const u64 ml = win & 0x1FFFFFFFFull;   // bits [j-32, j] (bit 32 = j)
        const u64 mr = win >> 32;              // bits [j, j+31]
        int dd;
        if (ml | mr) {
          const int dl = ml ? (__builtin_clzll(ml) - 31) : 512;
          const int dr = mr ? (int)__builtin_ctzll(mr) : 512;
          dd = min(dl, dr);
        } else {
          // exact rare fallback: full 4-word scan both directions
          int dl = 512, dr = 512;
#pragma unroll
          for (int w2 = 3; w2 >= 0; --w2) {
            if (w2 * 64 <= j) {
              u64 m = M[1 + w2];
              if (w2 == (j >> 6)) {
                const int r6 = j & 63;
                m &= (r6 == 63) ? ~0ull : ((1ull << (r6 + 1)) - 1ull);
              }
              if (m && dl == 512) dl = j - (w2 * 64 + 63 - __builtin_clzll(m));
            }
          }
#pragma unroll
          for (int w2 = 0; w2 < 4; ++w2) {
            if (w2 * 64 + 63 >= j) {
              u64 m = M[1 + w2];
              if (w2 == (j >> 6)) m &= ~((1ull << (j & 63)) - 1ull);
              if (m && dr == 512) dr = w2 * 64 + (int)__builtin_ctzll(m) - j;
            }
          }
          dd = min(min(dl, dr), 512);
        }
        dd = min(dd, 255);        // sat: only perturbs values > 81 (see 5)
        dv[c] = (u16)(dd * dd);
      }
      sq.x = dv[0]; sq.y = dv[1]; sq.z = dv[2]; sq.w = dv[3];
    }
    s2[r][jj] = sq;
  }
  __syncthreads();

  // ---- 4. sliding column window: rows r = w*4 .. w*4+19 feed acc[0..3] ----
  u16x4 acc[4];
#pragma unroll
  for (int m = 0; m < 4; ++m) acc[m] = (u16x4){0xFFFF, 0xFFFF, 0xFFFF, 0xFFFF};
#pragma unroll
  for (int rr = 0; rr < 20; ++rr) {
    const u16x4 val = s2[w * 4 + rr][jj];
#pragma unroll
    for (int m = 0; m < 4; ++m) {
      const int kq = rr - m;
      if (kq >= 0 && kq <= 16) {  // compile-time predicate
        const int dd = (8 - kq) * (8 - kq);
        const u16x4 ddv = {(u16)dd, (u16)dd, (u16)dd, (u16)dd};
        acc[m] = __builtin_elementwise_min(acc[m], val + ddv);
      }
    }
  }

  // ---- 5+6. per-pixel exactness check, softmax, loss ----
  float contrib = 0.0f;
#pragma unroll
  for (int m = 0; m < 4; ++m) {
    const int i = i0 + w * 4 + m;
    int d0 = acc[m].x, d1 = acc[m].y, d2 = acc[m].z, d3 = acc[m].w;
    // excluded k have (i-k)^2 >= 81: min <= 81 -> provably exact.
    if (max(max(d0, d1), max(d2, d3)) > 81) {   // P ~ 1e-18, exact if taken
      d0 = 0x7fffffff; d1 = 0x7fffffff; d2 = 0x7fffffff; d3 = 0x7fffffff;
      const int* tp = tgt + n * (Hh * Ww);
      for (int p = 0; p < Hh * Ww; ++p) {
        const int t = tp[p];
        const int dy = i - (p >> 8);
        const int dx = j - (p & 255);
        const int dd2 = dy * dy + dx * dx;
        d0 = (t == 0) ? min(d0, dd2) : d0;
        d1 = (t == 1) ? min(d1, dd2) : d1;
        d2 = (t == 2) ? min(d2, dd2) : d2;
        d3 = (t == 3) ? min(d3, dd2) : d3;
      }
    }
    const float f0 = (float)d0, f1 = (float)d1;   // exact: < 2^24
    const float f2 = (float)d2, f3 = (float)d3;
    const float mx = fmaxf(fmaxf(x[m][0], x[m][1]), fmaxf(x[m][2], x[m][3]));
    const float e0 = __expf(x[m][0] - mx), e1 = __expf(x[m][1] - mx);
    const float e2 = __expf(x[m][2] - mx), e3 = __expf(x[m][3] - mx);
    const float rs = 1.0f / (e0 + e1 + e2 + e3);
    const float p0 = e0 * rs, p1 = e1 * rs, p2 = e2 * rs, p3 = e3 * rs;
    // own-class d is exactly 0; exclude it for dbar
    const int q0 = (d0 == 0) ? 0x7fffffff : d0;
    const int q1 = (d1 == 0) ? 0x7fffffff : d1;
    const int q2 = (d2 == 0) ? 0x7fffffff : d2;
    const int q3 = (d3 == 0) ? 0x7fffffff : d3;
    const float dbar = (float)min(min(q0, q1), min(q2, q3));
    const float pt = (d0 == 0) ? p0 : (d1 == 0) ? p1 : (d2 == 0) ? p2 : p3;
    contrib += pt * sqrtf(dbar) -
               (p0 * sqrtf(f0) + p1 * sqrtf(f1) +
                p2 * sqrtf(f2) + p3 * sqrtf(f3));
  }

  // ---- block reduction (deterministic fixed order) ----
#pragma unroll
  for (int off = 32; off > 0; off >>= 1) contrib += __shfl_down(contrib, off);
  if (lane == 0) s_w[w] = contrib;
  __syncthreads();
  if (tid == 0) {
    partials[bid] = (s_w[0] + s_w[1]) + (s_w[2] + s_w[3]);  // plain store
  }
}

// ---------------------------------------------------------------------------
// Finalize: deterministic reduction of 512 partials + scaling
// ---------------------------------------------------------------------------
__global__ __launch_bounds__(256) void finalize_kernel(
    const float* __restrict__ partials, float* __restrict__ out) {
  __shared__ float s_red[256];
  const int tid = threadIdx.x;
  const float v0 = partials[tid];
  const float v1 = partials[tid + 256];
  s_red[tid] = v0 + v1;
  __syncthreads();
  for (int st = 128; st > 0; st >>= 1) {
    if (tid < st) s_red[tid] += s_red[tid + st];
    __syncthreads();
  }
  if (tid == 0)
    out[0] = s_red[0] / (float)(Cc * Nn) / (65536.0f + 1e-6f);
}

extern "C" void kernel_launch(void* const* d_in, const int* in_sizes, int n_in,
                              void* d_out, int out_size, void* d_ws, size_t ws_size,
                              hipStream_t stream) {
  const float* input = (const float*)d_in[0];   // [8,4,256,256] fp32 logits
  const int* target = (const int*)d_in[1];      // [8,256,256] int32
  float* out = (float*)d_out;                   // scalar fp32
  float* partials = (float*)((char*)d_ws + OFF_PART);

  merged_kernel<<<dim3(512), dim3(256), 0, stream>>>(target, input, partials);
  finalize_kernel<<<dim3(1), dim3(256), 0, stream>>>(partials, out);
}